// Round 3
// baseline (309.478 us; speedup 1.0000x reference)
//
#include <hip/hip_runtime.h>
#include <cstdint>
#include <cstddef>

#define HD 128
#define KD 256
#define TE 128
#define BLOCK 256

typedef __attribute__((ext_vector_type(8))) short bf16x8;
typedef __attribute__((ext_vector_type(4))) float f32x4;
typedef __attribute__((ext_vector_type(8))) unsigned short u16x8;

typedef const __attribute__((address_space(1))) void gv_t;
typedef __attribute__((address_space(3))) void lv_t;

__device__ __forceinline__ void gload16(const void* g, void* l) {
    __builtin_amdgcn_global_load_lds((gv_t*)g, (lv_t*)l, 16, 0, 0);
}

__device__ __forceinline__ unsigned short f2bf(float x) {   // RNE f32->bf16
    unsigned u = __float_as_uint(x);
    u = (u + 0x7fffu + ((u >> 16) & 1u)) >> 16;
    return (unsigned short)u;
}
__device__ __forceinline__ float bf2f(unsigned short x) {
    return __uint_as_float((unsigned)x << 16);
}

// ============ NEW PATH: per-node precompute + light edge gather ============

// pack B for uv_gemm: Bw[k][c] (128 x 256) where c<128 -> w1[k][c], c>=128 -> w1[128+k][c-128]
// frag layout: elem ((kt*16+nf)*64+lane)*8+j = Bw[kt*32+(lane>>4)*8+j][nf*16+(lane&15)]
__global__ void pack_B_kernel(const float* __restrict__ w1,
                              unsigned short* __restrict__ Bp) {
    const int tid = blockIdx.x * 256 + threadIdx.x;   // 0..4095
    const int lane = tid & 63, nf = (tid >> 6) & 15, kt = tid >> 10;
    const int col = nf * 16 + (lane & 15);
    const int k0 = kt * 32 + (lane >> 4) * 8;
    #pragma unroll
    for (int j = 0; j < 8; ++j) {
        const int k = k0 + j;
        const float v = (col < HD) ? w1[(size_t)k * HD + col]
                                   : w1[(size_t)(HD + k) * HD + (col - HD)];
        Bp[(size_t)tid * 8 + j] = f2bf(v);
    }
}

// UV[n][c] bf16, c<128: relu-input U' = z[n]@W1a + b1 ; c>=128: V = z[n]@W1b
__global__ __launch_bounds__(256, 1) void uv_gemm_kernel(
    const float* __restrict__ z, const unsigned short* __restrict__ Bp,
    const float* __restrict__ b1, unsigned short* __restrict__ UV, const int NN)
{
    __shared__ __attribute__((aligned(16))) unsigned short sA[128 * HD]; // 32KB swizzled
    char* sAb = (char*)sA;
    const int t = threadIdx.x, wave = t >> 6, l = t & 63;
    const int n0 = blockIdx.x * 128;

    // stage z tile (f32 -> bf16), swizzle: byte-in-row ^= (row&15)<<4
    {
        const int r = t >> 1, kh = t & 1;
        int n = n0 + r; if (n >= NN) n = NN - 1;
        const float* zr = z + (size_t)n * HD + kh * 64;
        #pragma unroll
        for (int q = 0; q < 16; ++q) {
            const float4 v = *(const float4*)(zr + q * 4);
            ushort4 o;
            o.x = f2bf(v.x); o.y = f2bf(v.y); o.z = f2bf(v.z); o.w = f2bf(v.w);
            const int byte = r * 256 + (kh * 64 + q * 4) * 2;
            *(ushort4*)(sAb + (byte ^ ((r & 15) << 4))) = o;
        }
    }
    __syncthreads();

    const int waveM = wave >> 1, waveN = wave & 1;
    f32x4 acc[4][8];
    #pragma unroll
    for (int nf = 0; nf < 8; ++nf) {
        const int c = waveN * 128 + nf * 16 + (l & 15);
        const float iv = (c < HD) ? b1[c] : 0.f;   // fold b1 into U half
        #pragma unroll
        for (int mf = 0; mf < 4; ++mf)
            #pragma unroll
            for (int j = 0; j < 4; ++j) acc[mf][nf][j] = iv;
    }

    #pragma unroll
    for (int kt = 0; kt < 4; ++kt) {
        bf16x8 bfr[8], af[4];
        #pragma unroll
        for (int nf = 0; nf < 8; ++nf)
            bfr[nf] = *(const bf16x8*)(Bp + (size_t)((kt * 16 + waveN * 8 + nf) * 64 + l) * 8);
        #pragma unroll
        for (int mf = 0; mf < 4; ++mf) {
            const int rr = waveM * 64 + mf * 16 + (l & 15);
            const int byte = rr * 256 + kt * 64 + (l >> 4) * 16;
            af[mf] = *(const bf16x8*)(sAb + (byte ^ ((rr & 15) << 4)));
        }
        #pragma unroll
        for (int mf = 0; mf < 4; ++mf)
            #pragma unroll
            for (int nf = 0; nf < 8; ++nf)
                acc[mf][nf] = __builtin_amdgcn_mfma_f32_16x16x32_bf16(
                    af[mf], bfr[nf], acc[mf][nf], 0, 0, 0);
    }

    // store: D layout col=l&15, row=(l>>4)*4+j ; 16-lane 32B segments
    #pragma unroll
    for (int mf = 0; mf < 4; ++mf)
        #pragma unroll
        for (int j = 0; j < 4; ++j) {
            const int rr = waveM * 64 + mf * 16 + (l >> 4) * 4 + j;
            const int n2 = n0 + rr;
            if (n2 < NN) {
                #pragma unroll
                for (int nf = 0; nf < 8; ++nf) {
                    const int c = waveN * 128 + nf * 16 + (l & 15);
                    UV[(size_t)n2 * KD + c] = f2bf(acc[mf][nf][j]);
                }
            }
        }
}

// per-edge: out = sigmoid( sum_c relu(U'[s,c]+V[d,c]) * w2[c] + b2 )
__global__ __launch_bounds__(256, 8) void edge_uv_kernel(
    const unsigned short* __restrict__ UV, const int* __restrict__ eli,
    const int E, const float* __restrict__ w2, const float* __restrict__ b2,
    float* __restrict__ out)
{
    const int e = blockIdx.x * 256 + threadIdx.x;
    if (e >= E) return;
    const int s = eli[e], d = eli[E + e];
    const u16x8* pu = (const u16x8*)(UV + (size_t)s * KD);       // U' half
    const u16x8* pv = (const u16x8*)(UV + (size_t)d * KD + HD);  // V half
    float acc = 0.f;
    #pragma unroll 4
    for (int j = 0; j < 16; ++j) {
        const u16x8 u = pu[j];
        const u16x8 v = pv[j];
        const float* w2j = w2 + j * 8;   // lane-uniform -> scalar loads
        #pragma unroll
        for (int m = 0; m < 8; ++m) {
            const float hf = fmaxf(bf2f(u[m]) + bf2f(v[m]), 0.f);
            acc = fmaf(hf, w2j[m], acc);
        }
    }
    const float val = acc + b2[0];
    out[e] = 1.f / (1.f + __expf(-val));
}

// ===================== FALLBACK 1: round-2 MFMA path =====================

__global__ void convert_z_kernel(const float* __restrict__ z,
                                 unsigned short* __restrict__ zb, int n4) {
    int i = blockIdx.x * blockDim.x + threadIdx.x;
    if (i < n4) {
        float4 v = ((const float4*)z)[i];
        ushort4 o;
        o.x = f2bf(v.x); o.y = f2bf(v.y); o.z = f2bf(v.z); o.w = f2bf(v.w);
        ((ushort4*)zb)[i] = o;
    }
}

__global__ void pack_w1_kernel(const float* __restrict__ w1,
                               unsigned short* __restrict__ w1p) {
    int tid = blockIdx.x * blockDim.x + threadIdx.x;
    int lane = tid & 63, nf = (tid >> 6) & 7, kt = tid >> 9;
    int col = nf * 16 + (lane & 15);
    int k0 = kt * 32 + (lane >> 4) * 8;
    #pragma unroll
    for (int j = 0; j < 8; ++j)
        w1p[(size_t)tid * 8 + j] = f2bf(w1[(size_t)(k0 + j) * HD + col]);
}

__global__ __launch_bounds__(BLOCK, 2) void edge_mfma_kernel(
    const unsigned short* __restrict__ zb, const unsigned short* __restrict__ w1p,
    const int* __restrict__ eli, const int E,
    const float* __restrict__ b1, const float* __restrict__ w2,
    const float* __restrict__ b2, float* __restrict__ out)
{
    __shared__ __attribute__((aligned(16))) unsigned short sZ[TE * KD];
    __shared__ __attribute__((aligned(16))) unsigned short sW[2][8 * 64 * 8];
    const int t = threadIdx.x, wave = t >> 6, l = t & 63;
    const int e0 = blockIdx.x * TE;
    #pragma unroll
    for (int q = 0; q < 16; ++q) {
        const int epair = wave * 32 + q * 2;
        const int r = epair + (l >> 5);
        int ge = e0 + r; if (ge >= E) ge = E - 1;
        const int ob = ((l & 31) * 16) ^ ((r & 7) << 4);
        const int node = (ob < 256) ? eli[ge] : eli[E + ge];
        gload16((const char*)zb + (size_t)node * 256 + (ob & 255), (char*)sZ + epair * 512);
    }
    #pragma unroll
    for (int q = 0; q < 2; ++q) {
        const int i = wave * 2 + q;
        gload16((const char*)w1p + i * 1024 + l * 16, (char*)sW[0] + i * 1024);
    }
    __syncthreads();
    const int waveM = wave >> 1, waveN = wave & 1;
    f32x4 acc[4][4];
    #pragma unroll
    for (int i = 0; i < 4; ++i)
        #pragma unroll
        for (int j = 0; j < 4; ++j) acc[i][j] = (f32x4)(0.f);
    for (int kt = 0; kt < 8; ++kt) {
        const int buf = kt & 1;
        if (kt < 7) {
            #pragma unroll
            for (int q = 0; q < 2; ++q) {
                const int i = wave * 2 + q;
                gload16((const char*)w1p + (size_t)(kt + 1) * 8192 + i * 1024 + l * 16,
                        (char*)sW[buf ^ 1] + i * 1024);
            }
        }
        bf16x8 af[4], bfr[4];
        #pragma unroll
        for (int mf = 0; mf < 4; ++mf) {
            const int r = waveM * 64 + mf * 16 + (l & 15);
            const int o = r * 512 + kt * 64 + ((l >> 4) * 16);
            af[mf] = *(const bf16x8*)((const char*)sZ + (o ^ ((r & 7) << 4)));
        }
        #pragma unroll
        for (int nf = 0; nf < 4; ++nf)
            bfr[nf] = *(const bf16x8*)((const char*)sW[buf] + (waveN * 4 + nf) * 1024 + l * 16);
        #pragma unroll
        for (int mf = 0; mf < 4; ++mf)
            #pragma unroll
            for (int nf = 0; nf < 4; ++nf)
                acc[mf][nf] = __builtin_amdgcn_mfma_f32_16x16x32_bf16(
                    af[mf], bfr[nf], acc[mf][nf], 0, 0, 0);
        __syncthreads();
    }
    float b1v[4], w2v[4];
    #pragma unroll
    for (int nf = 0; nf < 4; ++nf) {
        const int c = waveN * 64 + nf * 16 + (l & 15);
        b1v[nf] = b1[c]; w2v[nf] = w2[c];
    }
    float part[4][4];
    #pragma unroll
    for (int mf = 0; mf < 4; ++mf)
        #pragma unroll
        for (int j = 0; j < 4; ++j) {
            float p = 0.f;
            #pragma unroll
            for (int nf = 0; nf < 4; ++nf)
                p += fmaxf(acc[mf][nf][j] + b1v[nf], 0.f) * w2v[nf];
            #pragma unroll
            for (int m = 1; m <= 8; m <<= 1) p += __shfl_xor(p, m);
            part[mf][j] = p;
        }
    float* sRed = (float*)sW;
    if (waveN == 1 && (l & 15) == 0) {
        #pragma unroll
        for (int mf = 0; mf < 4; ++mf)
            #pragma unroll
            for (int j = 0; j < 4; ++j)
                sRed[waveM * 64 + mf * 16 + (l >> 4) * 4 + j] = part[mf][j];
    }
    __syncthreads();
    if (waveN == 0 && (l & 15) == 0) {
        const float bb2 = b2[0];
        #pragma unroll
        for (int mf = 0; mf < 4; ++mf)
            #pragma unroll
            for (int j = 0; j < 4; ++j) {
                const int row = waveM * 64 + mf * 16 + (l >> 4) * 4 + j;
                const int ge = e0 + row;
                if (ge < E) out[ge] = 1.f / (1.f + __expf(-(part[mf][j] + sRed[row] + bb2)));
            }
    }
}

// ===================== FALLBACK 2: fp32 VALU path =====================

__global__ __launch_bounds__(256, 2) void edge_decoder_fp32_kernel(
    const float* __restrict__ z, const int* __restrict__ eli, const int E,
    const float* __restrict__ w1, const float* __restrict__ b1,
    const float* __restrict__ w2, const float* __restrict__ b2,
    float* __restrict__ out)
{
    __shared__ float sZ[32][256];
    __shared__ float sW[2][32][128];
    const int t = threadIdx.x, wave = t >> 6, lane = t & 63;
    const int e0 = blockIdx.x * 32;
    #pragma unroll
    for (int q = 0; q < 8; ++q) {
        const int e = wave * 8 + q;
        int ge = e0 + e; if (ge >= E) ge = E - 1;
        const int node = (lane < 32) ? eli[ge] : eli[E + ge];
        gload16(z + (size_t)node * HD + (size_t)(lane & 31) * 4, &sZ[e][0]);
    }
    #pragma unroll
    for (int q = 0; q < 4; ++q) {
        const int inst = wave * 4 + q;
        gload16(w1 + inst * 256 + lane * 4, &sW[0][0][0] + inst * 256);
    }
    __syncthreads();
    const int cg = t & 31, eg = t >> 5, c0 = cg * 4;
    float acc[4][4] = {{0.f,0.f,0.f,0.f}};
    for (int kc = 0; kc < 8; ++kc) {
        const int buf = kc & 1;
        if (kc + 1 < 8) {
            const float* gw = w1 + (size_t)(kc + 1) * 32 * HD;
            #pragma unroll
            for (int q = 0; q < 4; ++q) {
                const int inst = wave * 4 + q;
                gload16(gw + inst * 256 + lane * 4, &sW[buf ^ 1][0][0] + inst * 256);
            }
        }
        #pragma unroll
        for (int k4 = 0; k4 < 8; ++k4) {
            float zr[4][4];
            #pragma unroll
            for (int i = 0; i < 4; ++i)
                *(float4*)(&zr[i][0]) = *(const float4*)(&sZ[eg*4+i][kc*32 + k4*4]);
            #pragma unroll
            for (int kk = 0; kk < 4; ++kk) {
                const float4 wv = *(const float4*)(&sW[buf][k4*4+kk][c0]);
                #pragma unroll
                for (int i = 0; i < 4; ++i) {
                    acc[i][0] = fmaf(zr[i][kk], wv.x, acc[i][0]);
                    acc[i][1] = fmaf(zr[i][kk], wv.y, acc[i][1]);
                    acc[i][2] = fmaf(zr[i][kk], wv.z, acc[i][2]);
                    acc[i][3] = fmaf(zr[i][kk], wv.w, acc[i][3]);
                }
            }
        }
        __syncthreads();
    }
    const float4 b1v = *(const float4*)(&b1[c0]);
    const float4 w2v = *(const float4*)(&w2[c0]);
    const float bb2 = b2[0];
    float part[4];
    #pragma unroll
    for (int i = 0; i < 4; ++i)
        part[i] = fmaxf(acc[i][0]+b1v.x,0.f)*w2v.x + fmaxf(acc[i][1]+b1v.y,0.f)*w2v.y
                + fmaxf(acc[i][2]+b1v.z,0.f)*w2v.z + fmaxf(acc[i][3]+b1v.w,0.f)*w2v.w;
    #pragma unroll
    for (int m = 16; m >= 1; m >>= 1)
        #pragma unroll
        for (int i = 0; i < 4; ++i) part[i] += __shfl_xor(part[i], m, 32);
    if (cg == 0) {
        #pragma unroll
        for (int i = 0; i < 4; ++i) {
            const int ge = e0 + eg * 4 + i;
            if (ge < E) out[ge] = 1.0f / (1.0f + __expf(-(part[i] + bb2)));
        }
    }
}

extern "C" void kernel_launch(void* const* d_in, const int* in_sizes, int n_in,
                              void* d_out, int out_size, void* d_ws, size_t ws_size,
                              hipStream_t stream) {
    const float* z  = (const float*)d_in[0];
    const int* eli  = (const int*)d_in[1];
    const float* w1 = (const float*)d_in[2];
    const float* b1 = (const float*)d_in[3];
    const float* w2 = (const float*)d_in[4];
    const float* b2 = (const float*)d_in[5];
    float* out = (float*)d_out;

    const int E  = in_sizes[1] / 2;
    const int NN = in_sizes[0] / HD;

    const size_t uv_bytes  = (size_t)NN * KD * 2;        // 51.2 MB
    const size_t need_new  = uv_bytes + 65536;           // + packed B
    const size_t need_mid  = 65536 + (size_t)NN * HD * 2;

    if (ws_size >= need_new) {
        unsigned short* UV = (unsigned short*)d_ws;
        unsigned short* Bp = (unsigned short*)((char*)d_ws + uv_bytes);
        pack_B_kernel<<<16, 256, 0, stream>>>(w1, Bp);
        uv_gemm_kernel<<<(NN + 127) / 128, 256, 0, stream>>>(z, Bp, b1, UV, NN);
        edge_uv_kernel<<<(E + 255) / 256, 256, 0, stream>>>(UV, eli, E, w2, b2, out);
    } else if (ws_size >= need_mid) {
        unsigned short* w1p = (unsigned short*)d_ws;
        unsigned short* zb  = (unsigned short*)((char*)d_ws + 65536);
        const int n4 = NN * HD / 4;
        convert_z_kernel<<<(n4 + 255) / 256, 256, 0, stream>>>(z, zb, n4);
        pack_w1_kernel<<<16, 256, 0, stream>>>(w1, w1p);
        edge_mfma_kernel<<<(E + TE - 1) / TE, BLOCK, 0, stream>>>(
            zb, w1p, eli, E, b1, w2, b2, out);
    } else {
        edge_decoder_fp32_kernel<<<(E + 31) / 32, 256, 0, stream>>>(
            z, eli, E, w1, b1, w2, b2, out);
    }
}

// Round 4
// 82.760 us; speedup vs baseline: 3.7395x; 3.7395x over previous
//
#include <hip/hip_runtime.h>
#include <cstdint>
#include <cstddef>

#define HD 128
#define KD 256
#define TE 128
#define BLOCK 256

typedef __attribute__((ext_vector_type(8))) short bf16x8;
typedef __attribute__((ext_vector_type(4))) float f32x4;
typedef __attribute__((ext_vector_type(8))) unsigned short u16x8;
typedef __attribute__((ext_vector_type(4))) unsigned int u32x4;

typedef const __attribute__((address_space(1))) void gv_t;
typedef __attribute__((address_space(3))) void lv_t;

__device__ __forceinline__ void gload16(const void* g, void* l) {
    __builtin_amdgcn_global_load_lds((gv_t*)g, (lv_t*)l, 16, 0, 0);
}

__device__ __forceinline__ unsigned short f2bf(float x) {   // RNE f32->bf16
    unsigned u = __float_as_uint(x);
    u = (u + 0x7fffu + ((u >> 16) & 1u)) >> 16;
    return (unsigned short)u;
}

// ============ per-node precompute + coalesced edge gather ============

// pack B: Bw[k][c] (128x256): c<128 -> w1[k][c] (W1a), c>=128 -> w1[128+k][c-128] (W1b)
__global__ void pack_B_kernel(const float* __restrict__ w1,
                              unsigned short* __restrict__ Bp) {
    const int tid = blockIdx.x * 256 + threadIdx.x;   // 0..4095
    const int lane = tid & 63, nf = (tid >> 6) & 15, kt = tid >> 10;
    const int col = nf * 16 + (lane & 15);
    const int k0 = kt * 32 + (lane >> 4) * 8;
    #pragma unroll
    for (int j = 0; j < 8; ++j) {
        const int k = k0 + j;
        const float v = (col < HD) ? w1[(size_t)k * HD + col]
                                   : w1[(size_t)(HD + k) * HD + (col - HD)];
        Bp[(size_t)tid * 8 + j] = f2bf(v);
    }
}

// UV[n][c] bf16: c<128 -> U' = z[n]@W1a + b1 ; c>=128 -> V = z[n]@W1b
__global__ __launch_bounds__(256, 1) void uv_gemm_kernel(
    const float* __restrict__ z, const unsigned short* __restrict__ Bp,
    const float* __restrict__ b1, unsigned short* __restrict__ UV, const int NN)
{
    __shared__ __attribute__((aligned(16))) unsigned short sA[128 * HD];
    char* sAb = (char*)sA;
    const int t = threadIdx.x, wave = t >> 6, l = t & 63;
    const int n0 = blockIdx.x * 128;
    {
        const int r = t >> 1, kh = t & 1;
        int n = n0 + r; if (n >= NN) n = NN - 1;
        const float* zr = z + (size_t)n * HD + kh * 64;
        #pragma unroll
        for (int q = 0; q < 16; ++q) {
            const float4 v = *(const float4*)(zr + q * 4);
            ushort4 o;
            o.x = f2bf(v.x); o.y = f2bf(v.y); o.z = f2bf(v.z); o.w = f2bf(v.w);
            const int byte = r * 256 + (kh * 64 + q * 4) * 2;
            *(ushort4*)(sAb + (byte ^ ((r & 15) << 4))) = o;
        }
    }
    __syncthreads();

    const int waveM = wave >> 1, waveN = wave & 1;
    f32x4 acc[4][8];
    #pragma unroll
    for (int nf = 0; nf < 8; ++nf) {
        const int c = waveN * 128 + nf * 16 + (l & 15);
        const float iv = (c < HD) ? b1[c] : 0.f;
        #pragma unroll
        for (int mf = 0; mf < 4; ++mf)
            #pragma unroll
            for (int j = 0; j < 4; ++j) acc[mf][nf][j] = iv;
    }
    #pragma unroll
    for (int kt = 0; kt < 4; ++kt) {
        bf16x8 bfr[8], af[4];
        #pragma unroll
        for (int nf = 0; nf < 8; ++nf)
            bfr[nf] = *(const bf16x8*)(Bp + (size_t)((kt * 16 + waveN * 8 + nf) * 64 + l) * 8);
        #pragma unroll
        for (int mf = 0; mf < 4; ++mf) {
            const int rr = waveM * 64 + mf * 16 + (l & 15);
            const int byte = rr * 256 + kt * 64 + (l >> 4) * 16;
            af[mf] = *(const bf16x8*)(sAb + (byte ^ ((rr & 15) << 4)));
        }
        #pragma unroll
        for (int mf = 0; mf < 4; ++mf)
            #pragma unroll
            for (int nf = 0; nf < 8; ++nf)
                acc[mf][nf] = __builtin_amdgcn_mfma_f32_16x16x32_bf16(
                    af[mf], bfr[nf], acc[mf][nf], 0, 0, 0);
    }
    #pragma unroll
    for (int mf = 0; mf < 4; ++mf)
        #pragma unroll
        for (int j = 0; j < 4; ++j) {
            const int rr = waveM * 64 + mf * 16 + (l >> 4) * 4 + j;
            const int n2 = n0 + rr;
            if (n2 < NN) {
                #pragma unroll
                for (int nf = 0; nf < 8; ++nf) {
                    const int c = waveN * 128 + nf * 16 + (l & 15);
                    UV[(size_t)n2 * KD + c] = f2bf(acc[mf][nf][j]);
                }
            }
        }
}

// coalesced edge pass: 16 lanes per edge; lane cl owns cols cl*8..cl*8+7
__global__ __launch_bounds__(256, 8) void edge_uv_coal_kernel(
    const unsigned short* __restrict__ UV, const int* __restrict__ eli,
    const int E, const float* __restrict__ w2, const float* __restrict__ b2,
    float* __restrict__ out)
{
    const int t = threadIdx.x;
    const int cl = t & 15;
    const int gid = (blockIdx.x * 256 + t) >> 4;
    const int ngroups = (gridDim.x * 256) >> 4;

    float w2v[8];
    {
        const float4 wlo = *(const float4*)(w2 + cl * 8);
        const float4 whi = *(const float4*)(w2 + cl * 8 + 4);
        w2v[0] = wlo.x; w2v[1] = wlo.y; w2v[2] = wlo.z; w2v[3] = wlo.w;
        w2v[4] = whi.x; w2v[5] = whi.y; w2v[6] = whi.z; w2v[7] = whi.w;
    }
    const float bb2 = b2[0];

    int e = gid;
    if (e >= E) return;
    int s = eli[e], d = eli[E + e];
    u32x4 u = *(const u32x4*)(UV + (size_t)s * KD + cl * 8);
    u32x4 v = *(const u32x4*)(UV + (size_t)d * KD + HD + cl * 8);

    for (;;) {
        const int e2 = e + ngroups;
        u32x4 u2, v2;
        if (e2 < E) {   // prefetch next iteration's rows
            const int s2 = eli[e2], d2 = eli[E + e2];
            u2 = *(const u32x4*)(UV + (size_t)s2 * KD + cl * 8);
            v2 = *(const u32x4*)(UV + (size_t)d2 * KD + HD + cl * 8);
        }
        float acc = 0.f;
        #pragma unroll
        for (int m = 0; m < 4; ++m) {
            const float ulo = __uint_as_float(u[m] << 16);
            const float uhi = __uint_as_float(u[m] & 0xffff0000u);
            const float vlo = __uint_as_float(v[m] << 16);
            const float vhi = __uint_as_float(v[m] & 0xffff0000u);
            acc = fmaf(fmaxf(ulo + vlo, 0.f), w2v[2 * m],     acc);
            acc = fmaf(fmaxf(uhi + vhi, 0.f), w2v[2 * m + 1], acc);
        }
        #pragma unroll
        for (int msk = 1; msk <= 8; msk <<= 1) acc += __shfl_xor(acc, msk);
        if (cl == 0) out[e] = 1.f / (1.f + __expf(-(acc + bb2)));
        if (e2 >= E) break;
        e = e2; u = u2; v = v2;
    }
}

// ===================== FALLBACK 1: round-2 MFMA path =====================

__global__ void convert_z_kernel(const float* __restrict__ z,
                                 unsigned short* __restrict__ zb, int n4) {
    int i = blockIdx.x * blockDim.x + threadIdx.x;
    if (i < n4) {
        float4 v = ((const float4*)z)[i];
        ushort4 o;
        o.x = f2bf(v.x); o.y = f2bf(v.y); o.z = f2bf(v.z); o.w = f2bf(v.w);
        ((ushort4*)zb)[i] = o;
    }
}

__global__ void pack_w1_kernel(const float* __restrict__ w1,
                               unsigned short* __restrict__ w1p) {
    int tid = blockIdx.x * blockDim.x + threadIdx.x;
    int lane = tid & 63, nf = (tid >> 6) & 7, kt = tid >> 9;
    int col = nf * 16 + (lane & 15);
    int k0 = kt * 32 + (lane >> 4) * 8;
    #pragma unroll
    for (int j = 0; j < 8; ++j)
        w1p[(size_t)tid * 8 + j] = f2bf(w1[(size_t)(k0 + j) * HD + col]);
}

__global__ __launch_bounds__(BLOCK, 2) void edge_mfma_kernel(
    const unsigned short* __restrict__ zb, const unsigned short* __restrict__ w1p,
    const int* __restrict__ eli, const int E,
    const float* __restrict__ b1, const float* __restrict__ w2,
    const float* __restrict__ b2, float* __restrict__ out)
{
    __shared__ __attribute__((aligned(16))) unsigned short sZ[TE * KD];
    __shared__ __attribute__((aligned(16))) unsigned short sW[2][8 * 64 * 8];
    const int t = threadIdx.x, wave = t >> 6, l = t & 63;
    const int e0 = blockIdx.x * TE;
    #pragma unroll
    for (int q = 0; q < 16; ++q) {
        const int epair = wave * 32 + q * 2;
        const int r = epair + (l >> 5);
        int ge = e0 + r; if (ge >= E) ge = E - 1;
        const int ob = ((l & 31) * 16) ^ ((r & 7) << 4);
        const int node = (ob < 256) ? eli[ge] : eli[E + ge];
        gload16((const char*)zb + (size_t)node * 256 + (ob & 255), (char*)sZ + epair * 512);
    }
    #pragma unroll
    for (int q = 0; q < 2; ++q) {
        const int i = wave * 2 + q;
        gload16((const char*)w1p + i * 1024 + l * 16, (char*)sW[0] + i * 1024);
    }
    __syncthreads();
    const int waveM = wave >> 1, waveN = wave & 1;
    f32x4 acc[4][4];
    #pragma unroll
    for (int i = 0; i < 4; ++i)
        #pragma unroll
        for (int j = 0; j < 4; ++j) acc[i][j] = (f32x4)(0.f);
    for (int kt = 0; kt < 8; ++kt) {
        const int buf = kt & 1;
        if (kt < 7) {
            #pragma unroll
            for (int q = 0; q < 2; ++q) {
                const int i = wave * 2 + q;
                gload16((const char*)w1p + (size_t)(kt + 1) * 8192 + i * 1024 + l * 16,
                        (char*)sW[buf ^ 1] + i * 1024);
            }
        }
        bf16x8 af[4], bfr[4];
        #pragma unroll
        for (int mf = 0; mf < 4; ++mf) {
            const int r = waveM * 64 + mf * 16 + (l & 15);
            const int o = r * 512 + kt * 64 + ((l >> 4) * 16);
            af[mf] = *(const bf16x8*)((const char*)sZ + (o ^ ((r & 7) << 4)));
        }
        #pragma unroll
        for (int nf = 0; nf < 4; ++nf)
            bfr[nf] = *(const bf16x8*)((const char*)sW[buf] + (waveN * 4 + nf) * 1024 + l * 16);
        #pragma unroll
        for (int mf = 0; mf < 4; ++mf)
            #pragma unroll
            for (int nf = 0; nf < 4; ++nf)
                acc[mf][nf] = __builtin_amdgcn_mfma_f32_16x16x32_bf16(
                    af[mf], bfr[nf], acc[mf][nf], 0, 0, 0);
        __syncthreads();
    }
    float b1v[4], w2v[4];
    #pragma unroll
    for (int nf = 0; nf < 4; ++nf) {
        const int c = waveN * 64 + nf * 16 + (l & 15);
        b1v[nf] = b1[c]; w2v[nf] = w2[c];
    }
    float part[4][4];
    #pragma unroll
    for (int mf = 0; mf < 4; ++mf)
        #pragma unroll
        for (int j = 0; j < 4; ++j) {
            float p = 0.f;
            #pragma unroll
            for (int nf = 0; nf < 4; ++nf)
                p += fmaxf(acc[mf][nf][j] + b1v[nf], 0.f) * w2v[nf];
            #pragma unroll
            for (int m = 1; m <= 8; m <<= 1) p += __shfl_xor(p, m);
            part[mf][j] = p;
        }
    float* sRed = (float*)sW;
    if (waveN == 1 && (l & 15) == 0) {
        #pragma unroll
        for (int mf = 0; mf < 4; ++mf)
            #pragma unroll
            for (int j = 0; j < 4; ++j)
                sRed[waveM * 64 + mf * 16 + (l >> 4) * 4 + j] = part[mf][j];
    }
    __syncthreads();
    if (waveN == 0 && (l & 15) == 0) {
        const float bb2 = b2[0];
        #pragma unroll
        for (int mf = 0; mf < 4; ++mf)
            #pragma unroll
            for (int j = 0; j < 4; ++j) {
                const int row = waveM * 64 + mf * 16 + (l >> 4) * 4 + j;
                const int ge = e0 + row;
                if (ge < E) out[ge] = 1.f / (1.f + __expf(-(part[mf][j] + sRed[row] + bb2)));
            }
    }
}

// ===================== FALLBACK 2: fp32 VALU path =====================

__global__ __launch_bounds__(256, 2) void edge_decoder_fp32_kernel(
    const float* __restrict__ z, const int* __restrict__ eli, const int E,
    const float* __restrict__ w1, const float* __restrict__ b1,
    const float* __restrict__ w2, const float* __restrict__ b2,
    float* __restrict__ out)
{
    __shared__ float sZ[32][256];
    __shared__ float sW[2][32][128];
    const int t = threadIdx.x, wave = t >> 6, lane = t & 63;
    const int e0 = blockIdx.x * 32;
    #pragma unroll
    for (int q = 0; q < 8; ++q) {
        const int e = wave * 8 + q;
        int ge = e0 + e; if (ge >= E) ge = E - 1;
        const int node = (lane < 32) ? eli[ge] : eli[E + ge];
        gload16(z + (size_t)node * HD + (size_t)(lane & 31) * 4, &sZ[e][0]);
    }
    #pragma unroll
    for (int q = 0; q < 4; ++q) {
        const int inst = wave * 4 + q;
        gload16(w1 + inst * 256 + lane * 4, &sW[0][0][0] + inst * 256);
    }
    __syncthreads();
    const int cg = t & 31, eg = t >> 5, c0 = cg * 4;
    float acc[4][4] = {{0.f,0.f,0.f,0.f}};
    for (int kc = 0; kc < 8; ++kc) {
        const int buf = kc & 1;
        if (kc + 1 < 8) {
            const float* gw = w1 + (size_t)(kc + 1) * 32 * HD;
            #pragma unroll
            for (int q = 0; q < 4; ++q) {
                const int inst = wave * 4 + q;
                gload16(gw + inst * 256 + lane * 4, &sW[buf ^ 1][0][0] + inst * 256);
            }
        }
        #pragma unroll
        for (int k4 = 0; k4 < 8; ++k4) {
            float zr[4][4];
            #pragma unroll
            for (int i = 0; i < 4; ++i)
                *(float4*)(&zr[i][0]) = *(const float4*)(&sZ[eg*4+i][kc*32 + k4*4]);
            #pragma unroll
            for (int kk = 0; kk < 4; ++kk) {
                const float4 wv = *(const float4*)(&sW[buf][k4*4+kk][c0]);
                #pragma unroll
                for (int i = 0; i < 4; ++i) {
                    acc[i][0] = fmaf(zr[i][kk], wv.x, acc[i][0]);
                    acc[i][1] = fmaf(zr[i][kk], wv.y, acc[i][1]);
                    acc[i][2] = fmaf(zr[i][kk], wv.z, acc[i][2]);
                    acc[i][3] = fmaf(zr[i][kk], wv.w, acc[i][3]);
                }
            }
        }
        __syncthreads();
    }
    const float4 b1v = *(const float4*)(&b1[c0]);
    const float4 w2v = *(const float4*)(&w2[c0]);
    const float bb2 = b2[0];
    float part[4];
    #pragma unroll
    for (int i = 0; i < 4; ++i)
        part[i] = fmaxf(acc[i][0]+b1v.x,0.f)*w2v.x + fmaxf(acc[i][1]+b1v.y,0.f)*w2v.y
                + fmaxf(acc[i][2]+b1v.z,0.f)*w2v.z + fmaxf(acc[i][3]+b1v.w,0.f)*w2v.w;
    #pragma unroll
    for (int m = 16; m >= 1; m >>= 1)
        #pragma unroll
        for (int i = 0; i < 4; ++i) part[i] += __shfl_xor(part[i], m, 32);
    if (cg == 0) {
        #pragma unroll
        for (int i = 0; i < 4; ++i) {
            const int ge = e0 + eg * 4 + i;
            if (ge < E) out[ge] = 1.0f / (1.0f + __expf(-(part[i] + bb2)));
        }
    }
}

extern "C" void kernel_launch(void* const* d_in, const int* in_sizes, int n_in,
                              void* d_out, int out_size, void* d_ws, size_t ws_size,
                              hipStream_t stream) {
    const float* z  = (const float*)d_in[0];
    const int* eli  = (const int*)d_in[1];
    const float* w1 = (const float*)d_in[2];
    const float* b1 = (const float*)d_in[3];
    const float* w2 = (const float*)d_in[4];
    const float* b2 = (const float*)d_in[5];
    float* out = (float*)d_out;

    const int E  = in_sizes[1] / 2;
    const int NN = in_sizes[0] / HD;

    const size_t uv_bytes = (size_t)NN * KD * 2;
    const size_t need_new = uv_bytes + 65536;
    const size_t need_mid = 65536 + (size_t)NN * HD * 2;

    if (ws_size >= need_new) {
        unsigned short* UV = (unsigned short*)d_ws;
        unsigned short* Bp = (unsigned short*)((char*)d_ws + uv_bytes);
        pack_B_kernel<<<16, 256, 0, stream>>>(w1, Bp);
        uv_gemm_kernel<<<(NN + 127) / 128, 256, 0, stream>>>(z, Bp, b1, UV, NN);
        edge_uv_coal_kernel<<<2048, 256, 0, stream>>>(UV, eli, E, w2, b2, out);
    } else if (ws_size >= need_mid) {
        unsigned short* w1p = (unsigned short*)d_ws;
        unsigned short* zb  = (unsigned short*)((char*)d_ws + 65536);
        const int n4 = NN * HD / 4;
        convert_z_kernel<<<(n4 + 255) / 256, 256, 0, stream>>>(z, zb, n4);
        pack_w1_kernel<<<16, 256, 0, stream>>>(w1, w1p);
        edge_mfma_kernel<<<(E + TE - 1) / TE, BLOCK, 0, stream>>>(
            zb, w1p, eli, E, b1, w2, b2, out);
    } else {
        edge_decoder_fp32_kernel<<<(E + 31) / 32, 256, 0, stream>>>(
            z, eli, E, w1, b1, w2, b2, out);
    }
}